// Round 4
// baseline (1058.945 us; speedup 1.0000x reference)
//
#include <hip/hip_runtime.h>
#include <hip/hip_bf16.h>
#include <math.h>

// Problem constants (feature dims fixed by the reference).
#define IN_DIM 128
#define HID_DIM 128
#define OUT_DIM 64
#define NCLS 7

// ---------------------------------------------------------------------------
// K1: F0 = x @ W1   [N,128] = [N,128]@[128,128]
// ---------------------------------------------------------------------------
__global__ __launch_bounds__(256) void gemm1_kernel(
    const float* __restrict__ x, const float* __restrict__ W1,
    float* __restrict__ F0, int n) {
  __shared__ float xs[64 * 128];  // 32KB
  const int t = threadIdx.x;
  const int n0 = blockIdx.x * 64;

  for (int i = t; i < 64 * 128; i += 256) {
    int r = i >> 7, cc = i & 127;
    int gr = n0 + r;
    xs[i] = (gr < n) ? x[(size_t)gr * 128 + cc] : 0.0f;
  }
  __syncthreads();

  const int c = t & 127;
  const int half = t >> 7;  // 0 or 1
  float acc[32];
#pragma unroll
  for (int i = 0; i < 32; i++) acc[i] = 0.0f;

  for (int k0 = 0; k0 < 128; k0 += 8) {
    float w[8];
#pragma unroll
    for (int kk = 0; kk < 8; kk++) w[kk] = W1[(size_t)(k0 + kk) * 128 + c];
#pragma unroll
    for (int i = 0; i < 32; i++) {
      const int r = half + 2 * i;
#pragma unroll
      for (int kk = 0; kk < 8; kk++) acc[i] += xs[r * 128 + k0 + kk] * w[kk];
    }
  }
#pragma unroll
  for (int i = 0; i < 32; i++) {
    int gr = n0 + half + 2 * i;
    if (gr < n) F0[(size_t)gr * 128 + c] = acc[i];
  }
}

// ---------------------------------------------------------------------------
// K2: per-node attention dots
// ---------------------------------------------------------------------------
__global__ __launch_bounds__(256) void dots_kernel(
    const float* __restrict__ F0, const float* __restrict__ a_src,
    const float* __restrict__ a_dst, float* __restrict__ as_dot,
    float* __restrict__ ad_dot, int n) {
  const int wid = (blockIdx.x * blockDim.x + threadIdx.x) >> 6;
  const int lane = threadIdx.x & 63;
  if (wid >= n) return;
  float f0 = F0[(size_t)wid * 128 + lane];
  float f1 = F0[(size_t)wid * 128 + 64 + lane];
  float s = f0 * a_src[lane] + f1 * a_src[64 + lane];
  float d = f0 * a_dst[lane] + f1 * a_dst[64 + lane];
  for (int m = 32; m; m >>= 1) {
    s += __shfl_xor(s, m);
    d += __shfl_xor(d, m);
  }
  if (lane == 0) {
    as_dot[wid] = s;
    ad_dot[wid] = d;
  }
}

// ---------------------------------------------------------------------------
// K3: degree histogram over dst
// ---------------------------------------------------------------------------
__global__ __launch_bounds__(256) void hist_kernel(const int* __restrict__ dst,
                                                   int* __restrict__ deg,
                                                   int e) {
  int i = blockIdx.x * blockDim.x + threadIdx.x;
  if (i < e) atomicAdd(&deg[dst[i]], 1);
}

// ---------------------------------------------------------------------------
// K4a/b/c: multi-block exclusive scan of deg -> rowptr (+cursor copy).
// ---------------------------------------------------------------------------
__global__ __launch_bounds__(256) void scan1_kernel(const int* __restrict__ deg,
                                                    int* __restrict__ bsum,
                                                    int n) {
  __shared__ int lds[256];
  const int b = blockIdx.x, t = threadIdx.x;
  const int base = b * 1024 + t * 4;
  int s = 0;
#pragma unroll
  for (int u = 0; u < 4; u++) {
    int i = base + u;
    if (i < n) s += deg[i];
  }
  lds[t] = s;
  __syncthreads();
  for (int off = 128; off; off >>= 1) {
    if (t < off) lds[t] += lds[t + off];
    __syncthreads();
  }
  if (t == 0) bsum[b] = lds[0];
}

__global__ __launch_bounds__(1024) void scan2_kernel(
    const int* __restrict__ bsum, int* __restrict__ boff,
    int* __restrict__ rowptr, int nb, int n) {
  __shared__ int lds[1024];
  const int t = threadIdx.x;
  int v = (t < nb) ? bsum[t] : 0;
  lds[t] = v;
  __syncthreads();
  for (int off = 1; off < 1024; off <<= 1) {
    int add = (t >= off) ? lds[t - off] : 0;
    __syncthreads();
    lds[t] += add;
    __syncthreads();
  }
  if (t < nb) boff[t] = lds[t] - v;  // exclusive
  if (t == nb - 1) rowptr[n] = lds[t];
}

__global__ __launch_bounds__(256) void scan3_kernel(
    const int* __restrict__ deg, const int* __restrict__ boff,
    int* __restrict__ rowptr, int* __restrict__ cursor, int n) {
  __shared__ int lds[256];
  const int b = blockIdx.x, t = threadIdx.x;
  const int base = b * 1024 + t * 4;
  int v[4];
  int s = 0;
#pragma unroll
  for (int u = 0; u < 4; u++) {
    int i = base + u;
    v[u] = (i < n) ? deg[i] : 0;
    s += v[u];
  }
  lds[t] = s;
  __syncthreads();
  for (int off = 1; off < 256; off <<= 1) {
    int add = (t >= off) ? lds[t - off] : 0;
    __syncthreads();
    lds[t] += add;
    __syncthreads();
  }
  int run = boff[b] + lds[t] - s;
#pragma unroll
  for (int u = 0; u < 4; u++) {
    int i = base + u;
    if (i < n) {
      rowptr[i] = run;
      cursor[i] = run;
      run += v[u];
    }
  }
}

// ---------------------------------------------------------------------------
// K5: scatter edges into CSR slots (store src per slot).
// ---------------------------------------------------------------------------
__global__ __launch_bounds__(256) void scatter_kernel(
    const int* __restrict__ src, const int* __restrict__ dst,
    int* __restrict__ cursor, int* __restrict__ esrc, int e) {
  int i = blockIdx.x * blockDim.x + threadIdx.x;
  if (i < e) {
    int pos = atomicAdd(&cursor[dst[i]], 1);
    esrc[pos] = src[i];
  }
}

// ---------------------------------------------------------------------------
// K6: GAT layer 1. One wave per dst node.
// Fast path (deg<=64): ONE gather of esrc/as_dot; logits in registers;
// butterfly max+sum; then 8-edge-group gather (8 lanes/edge, 16 dims/lane,
// 32 float4 gathers in flight).
// ---------------------------------------------------------------------------
__global__ __launch_bounds__(256) void gat1_kernel(
    const float* __restrict__ F0, const float* __restrict__ as_dot,
    const float* __restrict__ ad_dot, const int* __restrict__ rowptr,
    const int* __restrict__ esrc, const float* __restrict__ b1,
    float* __restrict__ alpha, float* __restrict__ Z0out, int n) {
  const int wid = (blockIdx.x * blockDim.x + threadIdx.x) >> 6;
  const int lane = threadIdx.x & 63;
  if (wid >= n) return;
  const int start = rowptr[wid];
  const int end = rowptr[wid + 1];
  const int deg = end - start;
  const float adn = ad_dot[wid];

  if (deg <= 64) {
    // ---- fused softmax: one pass, logits in a register ----
    const int j = start + lane;
    const bool act = (j < end);
    const int sj = act ? esrc[j] : 0;
    float z = -INFINITY;
    if (act) {
      z = as_dot[sj] + adn;
      z = (z > 0.0f) ? z : 0.2f * z;
    }
    float lmax = z;
    for (int m = 32; m; m >>= 1) lmax = fmaxf(lmax, __shfl_xor(lmax, m));
    const float ez = act ? expf(z - lmax) : 0.0f;
    float lsum = ez;
    for (int m = 32; m; m >>= 1) lsum += __shfl_xor(lsum, m);
    const float aj = ez * (1.0f / (lsum + 1e-16f));
    if (act) alpha[j] = aj;

    // ---- gather: group g (0..7) owns edge base+g; lane l (0..7) owns dims
    // [16l,16l+16) ----
    const int g = lane >> 3;
    const int l = lane & 7;
    float4 a0 = {0.f, 0.f, 0.f, 0.f}, a1 = {0.f, 0.f, 0.f, 0.f};
    float4 a2v = {0.f, 0.f, 0.f, 0.f}, a3 = {0.f, 0.f, 0.f, 0.f};
    for (int base = 0; base < deg; base += 8) {
      const int e = base + g;  // <= 63 always (base <= 56)
      const float we = __shfl(aj, e);
      const int se = __shfl(sj, e);
      if (e < deg) {
        const float* fr = &F0[(size_t)se * 128 + l * 16];
        const float4 u0 = *(const float4*)(fr);
        const float4 u1 = *(const float4*)(fr + 4);
        const float4 u2 = *(const float4*)(fr + 8);
        const float4 u3 = *(const float4*)(fr + 12);
        a0.x += we * u0.x; a0.y += we * u0.y; a0.z += we * u0.z; a0.w += we * u0.w;
        a1.x += we * u1.x; a1.y += we * u1.y; a1.z += we * u1.z; a1.w += we * u1.w;
        a2v.x += we * u2.x; a2v.y += we * u2.y; a2v.z += we * u2.z; a2v.w += we * u2.w;
        a3.x += we * u3.x; a3.y += we * u3.y; a3.z += we * u3.z; a3.w += we * u3.w;
      }
    }
    // merge the 8 groups (same l across g)
#pragma unroll
    for (int m = 8; m <= 32; m <<= 1) {
      a0.x += __shfl_xor(a0.x, m); a0.y += __shfl_xor(a0.y, m);
      a0.z += __shfl_xor(a0.z, m); a0.w += __shfl_xor(a0.w, m);
      a1.x += __shfl_xor(a1.x, m); a1.y += __shfl_xor(a1.y, m);
      a1.z += __shfl_xor(a1.z, m); a1.w += __shfl_xor(a1.w, m);
      a2v.x += __shfl_xor(a2v.x, m); a2v.y += __shfl_xor(a2v.y, m);
      a2v.z += __shfl_xor(a2v.z, m); a2v.w += __shfl_xor(a2v.w, m);
      a3.x += __shfl_xor(a3.x, m); a3.y += __shfl_xor(a3.y, m);
      a3.z += __shfl_xor(a3.z, m); a3.w += __shfl_xor(a3.w, m);
    }
    if (g == 0) {
      const float* bp = &b1[l * 16];
      const float4 c0 = *(const float4*)(bp);
      const float4 c1 = *(const float4*)(bp + 4);
      const float4 c2 = *(const float4*)(bp + 8);
      const float4 c3 = *(const float4*)(bp + 12);
      float* op = &Z0out[(size_t)wid * 128 + l * 16];
      float4 o0 = {a0.x + c0.x, a0.y + c0.y, a0.z + c0.z, a0.w + c0.w};
      float4 o1 = {a1.x + c1.x, a1.y + c1.y, a1.z + c1.z, a1.w + c1.w};
      float4 o2 = {a2v.x + c2.x, a2v.y + c2.y, a2v.z + c2.z, a2v.w + c2.w};
      float4 o3 = {a3.x + c3.x, a3.y + c3.y, a3.z + c3.z, a3.w + c3.w};
      *(float4*)(op) = o0;
      *(float4*)(op + 4) = o1;
      *(float4*)(op + 8) = o2;
      *(float4*)(op + 12) = o3;
    }
    return;
  }

  // ---- fallback (deg > 64): 3-pass strided softmax + 4x16 gather ----
  float lmax = -INFINITY;
  for (int j = start + lane; j < end; j += 64) {
    int s = esrc[j];
    float z = as_dot[s] + adn;
    z = (z > 0.0f) ? z : 0.2f * z;
    lmax = fmaxf(lmax, z);
  }
  for (int m = 32; m; m >>= 1) lmax = fmaxf(lmax, __shfl_xor(lmax, m));

  float lsum = 0.0f;
  for (int j = start + lane; j < end; j += 64) {
    int s = esrc[j];
    float z = as_dot[s] + adn;
    z = (z > 0.0f) ? z : 0.2f * z;
    lsum += expf(z - lmax);
  }
  for (int m = 32; m; m >>= 1) lsum += __shfl_xor(lsum, m);
  const float inv = 1.0f / (lsum + 1e-16f);

  const int g = lane >> 4;
  const int l = lane & 15;
  float4 accA = {0.f, 0.f, 0.f, 0.f};
  float4 accB = {0.f, 0.f, 0.f, 0.f};
  for (int base = start; base < end; base += 4) {
    const int j = base + g;
    const bool act = (j < end);
    const int sj = act ? esrc[j] : 0;
    float aj = 0.0f;
    if (act) {
      float z = as_dot[sj] + adn;
      z = (z > 0.0f) ? z : 0.2f * z;
      aj = expf(z - lmax) * inv;
      if (l == 0) alpha[j] = aj;
    }
    const float4 vA = *(const float4*)&F0[(size_t)sj * 128 + l * 8];
    const float4 vB = *(const float4*)&F0[(size_t)sj * 128 + l * 8 + 4];
    accA.x += aj * vA.x; accA.y += aj * vA.y;
    accA.z += aj * vA.z; accA.w += aj * vA.w;
    accB.x += aj * vB.x; accB.y += aj * vB.y;
    accB.z += aj * vB.z; accB.w += aj * vB.w;
  }
#pragma unroll
  for (int m = 16; m <= 32; m <<= 1) {
    accA.x += __shfl_xor(accA.x, m); accA.y += __shfl_xor(accA.y, m);
    accA.z += __shfl_xor(accA.z, m); accA.w += __shfl_xor(accA.w, m);
    accB.x += __shfl_xor(accB.x, m); accB.y += __shfl_xor(accB.y, m);
    accB.z += __shfl_xor(accB.z, m); accB.w += __shfl_xor(accB.w, m);
  }
  if (g == 0) {
    const float4 bA = *(const float4*)&b1[l * 8];
    const float4 bB = *(const float4*)&b1[l * 8 + 4];
    float4 oA = {accA.x + bA.x, accA.y + bA.y, accA.z + bA.z, accA.w + bA.w};
    float4 oB = {accB.x + bB.x, accB.y + bB.y, accB.z + bB.z, accB.w + bB.w};
    *(float4*)&Z0out[(size_t)wid * 128 + l * 8] = oA;
    *(float4*)&Z0out[(size_t)wid * 128 + l * 8 + 4] = oB;
  }
}

// ---------------------------------------------------------------------------
// K7: centroid partial sums (stage 1) + reduce (stage 2, 7 blocks).
// ---------------------------------------------------------------------------
#define CNB 256
__global__ __launch_bounds__(128) void centroid_partial_kernel(
    const float* __restrict__ Z0out, const int* __restrict__ y,
    float* __restrict__ partial, float* __restrict__ ccnt, int n, int per) {
  const int t = threadIdx.x;  // feature 0..127
  const int b = blockIdx.x;
  const int n0 = b * per;
  const int n1 = min(n0 + per, n);
  float a[NCLS];
#pragma unroll
  for (int k = 0; k < NCLS; k++) a[k] = 0.0f;
  int cnt[NCLS];
#pragma unroll
  for (int k = 0; k < NCLS; k++) cnt[k] = 0;

#pragma unroll 4
  for (int i = n0; i < n1; i++) {
    const int c = y[i];
    const float v = Z0out[(size_t)i * 128 + t];
#pragma unroll
    for (int k = 0; k < NCLS; k++) a[k] += (c == k) ? v : 0.0f;
    if (t == 0) {
#pragma unroll
      for (int k = 0; k < NCLS; k++) cnt[k] += (c == k) ? 1 : 0;
    }
  }
#pragma unroll
  for (int k = 0; k < NCLS; k++)
    partial[((size_t)b * NCLS + k) * 128 + t] = a[k];
  if (t == 0) {
#pragma unroll
    for (int k = 0; k < NCLS; k++) atomicAdd(&ccnt[k], (float)cnt[k]);
  }
}

__global__ __launch_bounds__(128) void centroid_reduce_kernel(
    const float* __restrict__ partial, const float* __restrict__ ccnt,
    float* __restrict__ ca, int nb) {
  const int k = blockIdx.x;   // class
  const int t = threadIdx.x;  // feature
  float s = 0.0f;
#pragma unroll 8
  for (int b = 0; b < nb; b++)
    s += partial[((size_t)b * NCLS + k) * 128 + t];
  ca[k * 128 + t] = s / (ccnt[k] + 1e-12f);
}

// ---------------------------------------------------------------------------
// K9: phi_Z, phi_X, S, diff, v. One wave per node.
// ---------------------------------------------------------------------------
__global__ __launch_bounds__(256) void phi_v_kernel(
    const float* __restrict__ Z0out, const float* __restrict__ x,
    const float* __restrict__ ca, const float* __restrict__ cb,
    const float* __restrict__ Q, const int* __restrict__ y,
    float* __restrict__ vbuf, float* __restrict__ phi_out, int n) {
  const int wid = (blockIdx.x * blockDim.x + threadIdx.x) >> 6;
  const int lane = threadIdx.x & 63;
  if (wid >= n) return;
  const float z0 = Z0out[(size_t)wid * 128 + lane];
  const float z1 = Z0out[(size_t)wid * 128 + 64 + lane];
  const float x0 = x[(size_t)wid * 128 + lane];
  const float x1 = x[(size_t)wid * 128 + 64 + lane];

  float sZ[NCLS], sX[NCLS];
#pragma unroll
  for (int k = 0; k < NCLS; k++) {
    float d0 = z0 - ca[k * 128 + lane];
    float d1 = z1 - ca[k * 128 + 64 + lane];
    sZ[k] = d0 * d0 + d1 * d1;
    float e0 = x0 - cb[k * 128 + lane];
    float e1 = x1 - cb[k * 128 + 64 + lane];
    sX[k] = e0 * e0 + e1 * e1;
  }
  for (int m = 32; m; m >>= 1) {
#pragma unroll
    for (int k = 0; k < NCLS; k++) {
      sZ[k] += __shfl_xor(sZ[k], m);
      sX[k] += __shfl_xor(sX[k], m);
    }
  }
  float distZ[NCLS], phiZ[NCLS];
  float sumZ = 0.0f, sumX = 0.0f, S = 0.0f;
#pragma unroll
  for (int k = 0; k < NCLS; k++) {
    distZ[k] = sqrtf(sZ[k]);
    float sc = expf(-distZ[k]) + 1e-10f;
    phiZ[k] = sc;
    sumZ += sc;
    float dx = sqrtf(sX[k]);
    float scx = expf(-dx) + 1e-10f;
    S += logf(scx);
    sumX += scx;
  }
  S -= 7.0f * logf(sumX);
  const float invZ = 1.0f / sumZ;
#pragma unroll
  for (int k = 0; k < NCLS; k++) phiZ[k] *= invZ;

  const int yc = y[wid];
  float w[NCLS];
  float W = 0.0f;
#pragma unroll
  for (int k = 0; k < NCLS; k++) {
    float diff = phiZ[k] * S - logf(Q[yc * NCLS + k]);
    w[k] = phiZ[k] * diff;
    W += w[k];
  }
  float v0 = 0.0f, v1 = 0.0f;
#pragma unroll
  for (int k = 0; k < NCLS; k++) {
    float coef = -(w[k] - W * phiZ[k]) / (distZ[k] + 1e-12f);
    v0 += coef * (z0 - ca[k * 128 + lane]);
    v1 += coef * (z1 - ca[k * 128 + 64 + lane]);
  }
  vbuf[(size_t)wid * 128 + lane] = v0;
  vbuf[(size_t)wid * 128 + 64 + lane] = v1;

  if (lane < NCLS) {
    float pv = (lane == 0) ? phiZ[0]
              : (lane == 1) ? phiZ[1]
              : (lane == 2) ? phiZ[2]
              : (lane == 3) ? phiZ[3]
              : (lane == 4) ? phiZ[4]
              : (lane == 5) ? phiZ[5]
                            : phiZ[6];
    phi_out[(size_t)wid * NCLS + lane] = pv;
  }
}

// ---------------------------------------------------------------------------
// K10: h2 = elu(Z0) @ W2   [N,64]
// ---------------------------------------------------------------------------
__global__ __launch_bounds__(256) void gemm2_kernel(
    const float* __restrict__ Z0out, const float* __restrict__ W2,
    float* __restrict__ h2, int n) {
  __shared__ float w2s[128 * 64];  // 32KB
  __shared__ float xs[16 * 128];   // 8KB
  const int t = threadIdx.x;
  for (int i = t; i < 128 * 64; i += 256) w2s[i] = W2[i];
  const int n0 = blockIdx.x * 16;
  for (int i = t; i < 16 * 128; i += 256) {
    int r = i >> 7, cc = i & 127;
    int gr = n0 + r;
    float zv = (gr < n) ? Z0out[(size_t)gr * 128 + cc] : 0.0f;
    xs[i] = (zv > 0.0f) ? zv : (expf(zv) - 1.0f);  // elu
  }
  __syncthreads();
  const int c = t & 63;
  const int rb = t >> 6;  // 0..3
  float acc[4] = {0.0f, 0.0f, 0.0f, 0.0f};
  for (int k = 0; k < 128; k++) {
    float wv = w2s[k * 64 + c];
#pragma unroll
    for (int i = 0; i < 4; i++) acc[i] += xs[(rb + 4 * i) * 128 + k] * wv;
  }
#pragma unroll
  for (int i = 0; i < 4; i++) {
    int gr = n0 + rb + 4 * i;
    if (gr < n) h2[(size_t)gr * 64 + c] = acc[i];
  }
}

// ---------------------------------------------------------------------------
// K11: conv2 gather. One wave per dst node; 8 edges concurrently (8 lanes
// each, 16 dims/lane => 32 float4 gathers in flight). Dot in-group (3 shfl),
// then 64-lane h2 accumulation with uniform-branch skip of zero weights.
// ---------------------------------------------------------------------------
__global__ __launch_bounds__(256) void conv2_kernel(
    const float* __restrict__ F0, const float* __restrict__ vbuf,
    const float* __restrict__ h2, const float* __restrict__ alpha,
    const int* __restrict__ rowptr, const int* __restrict__ esrc,
    const float* __restrict__ b2, float* __restrict__ outp, int n,
    float invN) {
  const int wid = (blockIdx.x * blockDim.x + threadIdx.x) >> 6;
  const int lane = threadIdx.x & 63;
  if (wid >= n) return;
  const int start = rowptr[wid];
  const int end = rowptr[wid + 1];
  const int g = lane >> 3;  // edge group 0..7
  const int l = lane & 7;   // dims [16l, 16l+16)
  float4 f0_[4];
#pragma unroll
  for (int u = 0; u < 4; u++)
    f0_[u] = *(const float4*)&F0[(size_t)wid * 128 + l * 16 + u * 4];
  float acc = 0.0f;  // output feature = lane
  for (int base = start; base < end; base += 8) {
    const int j = base + g;
    const bool act = (j < end);
    const int sj = act ? esrc[j] : 0;
    const float a = act ? alpha[j] : 0.0f;
    const float* vr = &vbuf[(size_t)sj * 128 + l * 16];
    const float4 v0 = *(const float4*)(vr);
    const float4 v1 = *(const float4*)(vr + 4);
    const float4 v2 = *(const float4*)(vr + 8);
    const float4 v3 = *(const float4*)(vr + 12);
    float p = v0.x * f0_[0].x + v0.y * f0_[0].y + v0.z * f0_[0].z +
              v0.w * f0_[0].w + v1.x * f0_[1].x + v1.y * f0_[1].y +
              v1.z * f0_[1].z + v1.w * f0_[1].w + v2.x * f0_[2].x +
              v2.y * f0_[2].y + v2.z * f0_[2].z + v2.w * f0_[2].w +
              v3.x * f0_[3].x + v3.y * f0_[3].y + v3.z * f0_[3].z +
              v3.w * f0_[3].w;
    p += __shfl_xor(p, 1);
    p += __shfl_xor(p, 2);
    p += __shfl_xor(p, 4);
    const float B1 = a - p * invN;
    const float w = act ? (B1 / (fabsf(B1) + 1e-16f)) : 0.0f;
#pragma unroll
    for (int g2 = 0; g2 < 8; g2++) {
      const float wg = __shfl(w, g2 * 8);  // wave-uniform
      if (wg != 0.0f) {
        const int sg = __shfl(sj, g2 * 8);
        acc += wg * h2[(size_t)sg * 64 + lane];
      }
    }
  }
  outp[(size_t)wid * 64 + lane] = acc + b2[lane];
}

// ---------------------------------------------------------------------------
extern "C" void kernel_launch(void* const* d_in, const int* in_sizes, int n_in,
                              void* d_out, int out_size, void* d_ws,
                              size_t ws_size, hipStream_t stream) {
  const float* x = (const float*)d_in[0];
  const int* ei = (const int*)d_in[1];
  const int* y = (const int*)d_in[2];
  const float* cb = (const float*)d_in[3];
  const float* Q = (const float*)d_in[4];
  const float* W1 = (const float*)d_in[5];
  const float* a_src = (const float*)d_in[6];
  const float* a_dst = (const float*)d_in[7];
  const float* b1 = (const float*)d_in[8];
  const float* W2 = (const float*)d_in[9];
  const float* b2 = (const float*)d_in[10];

  const int N = in_sizes[2];       // 100000
  const int E = in_sizes[1] / 2;   // 1600000
  const int* srcp = ei;
  const int* dstp = ei + E;

  // workspace layout
  float* F0 = (float*)d_ws;                    // N*128
  float* as_dot = F0 + (size_t)N * 128;        // N
  float* ad_dot = as_dot + N;                  // N
  float* alpha = ad_dot + N;                   // E
  float* vbuf = alpha + E;                     // N*128
  float* ca = vbuf + (size_t)N * 128;          // 7*128
  float* ccnt = ca + NCLS * 128;               // 16
  int* deg = (int*)(ccnt + 16);                // N
  int* rowptr = deg + N;                       // N+1
  int* cursor = rowptr + N + 1;                // N
  int* esrc = cursor + N;                      // E

  // scratch aliased into vbuf (all consumers finish before phi_v writes vbuf)
  float* partial = vbuf;                       // CNB*7*128 floats
  int* bsum = (int*)(vbuf + (size_t)CNB * NCLS * 128);  // 1024
  int* boff = bsum + 1024;                               // 1024

  // outputs (concatenated): out[N,64], h2[N,64], Z0[N,128], phi_Z[N,7]
  float* out_o = (float*)d_out;
  float* h2_o = out_o + (size_t)N * 64;
  float* z0_o = h2_o + (size_t)N * 64;
  float* phi_o = z0_o + (size_t)N * 128;

  hipMemsetAsync(deg, 0, (size_t)N * sizeof(int), stream);
  hipMemsetAsync(ccnt, 0, 16 * sizeof(float), stream);

  gemm1_kernel<<<(N + 63) / 64, 256, 0, stream>>>(x, W1, F0, N);
  dots_kernel<<<(N + 3) / 4, 256, 0, stream>>>(F0, a_src, a_dst, as_dot,
                                               ad_dot, N);
  hist_kernel<<<(E + 255) / 256, 256, 0, stream>>>(dstp, deg, E);
  {
    const int nb = (N + 1023) / 1024;
    scan1_kernel<<<nb, 256, 0, stream>>>(deg, bsum, N);
    scan2_kernel<<<1, 1024, 0, stream>>>(bsum, boff, rowptr, nb, N);
    scan3_kernel<<<nb, 256, 0, stream>>>(deg, boff, rowptr, cursor, N);
  }
  scatter_kernel<<<(E + 255) / 256, 256, 0, stream>>>(srcp, dstp, cursor, esrc,
                                                      E);
  gat1_kernel<<<(N + 3) / 4, 256, 0, stream>>>(F0, as_dot, ad_dot, rowptr,
                                               esrc, b1, alpha, z0_o, N);
  {
    const int per = (N + CNB - 1) / CNB;
    centroid_partial_kernel<<<CNB, 128, 0, stream>>>(z0_o, y, partial, ccnt, N,
                                                     per);
    centroid_reduce_kernel<<<NCLS, 128, 0, stream>>>(partial, ccnt, ca, CNB);
  }
  phi_v_kernel<<<(N + 3) / 4, 256, 0, stream>>>(z0_o, x, ca, cb, Q, y, vbuf,
                                                phi_o, N);
  gemm2_kernel<<<(N + 15) / 16, 256, 0, stream>>>(z0_o, W2, h2_o, N);
  conv2_kernel<<<(N + 3) / 4, 256, 0, stream>>>(F0, vbuf, h2_o, alpha, rowptr,
                                                esrc, b2, out_o, N,
                                                1.0f / (float)N);
}